// Round 16
// baseline (289.987 us; speedup 1.0000x reference)
//
#include <hip/hip_runtime.h>
#include <stdint.h>

#define NN 100000
#define NE 1600000
#define NR 4
#define NK (NN * NR)
#define FD 128
#define KA 512            // A matrix cols (rel blocks only; root appended as cols 512..639)
#define KT 640
#define NQ 1024
#define HIDN 256

#define NB 391            // dst buckets of 256 nodes
#define BSH 8
#define CAPB 8192         // per-bucket capacity (edges; avg 4096 + pad <= ~6200)
#define EPB 4096
#define NBLK1 ((NE + EPB - 1) / EPB)   // 391
#define MPAD 100096                    // NN rounded up to 128 (and 64)
#define LROWB 1280                     // LDS bytes per panel row (640 bf16)

using u16 = unsigned short;
using u32 = unsigned int;
typedef __attribute__((ext_vector_type(8))) __bf16 bf16x8;
typedef __attribute__((ext_vector_type(4))) float f32x4;

__device__ __forceinline__ u16 f2b(float f) {
    u32 u = __builtin_bit_cast(u32, f);
    u32 r = u + 0x7FFFu + ((u >> 16) & 1u);   // round-to-nearest-even
    return (u16)(r >> 16);
}
__device__ __forceinline__ float b2f_lo(u32 v) { return __builtin_bit_cast(float, v << 16); }
__device__ __forceinline__ float b2f_hi(u32 v) { return __builtin_bit_cast(float, v & 0xFFFF0000u); }
__device__ __forceinline__ u32 pack2(float a, float b) {
    return (u32)f2b(a) | ((u32)f2b(b) << 16);
}
// async global->LDS, 16B per lane; LDS dest = wave-uniform base + lane*16
__device__ __forceinline__ void gload_lds16(const void* g, void* l) {
    __builtin_amdgcn_global_load_lds((const __attribute__((address_space(1))) u32*)g,
                                     (__attribute__((address_space(3))) u32*)l, 16, 0, 0);
}

// ---------- phase 1: bucket scatter into fixed-capacity bucket-major segments ----------
__global__ __launch_bounds__(256) void bucket_scatter(const int* __restrict__ ei,
                                                      const int* __restrict__ et,
                                                      int* __restrict__ bcnt,
                                                      u32* __restrict__ bpack) {
    __shared__ int hist[NB];
    __shared__ int base[NB];
    int t = threadIdx.x;
    for (int i = t; i < NB; i += 256) hist[i] = 0;
    __syncthreads();
    int e0 = blockIdx.x * EPB;
    int rank[16];
    u32 pk[16];
    int bk[16];
#pragma unroll
    for (int j = 0; j < 16; ++j) {
        int e = e0 + j * 256 + t;
        bk[j] = -1;
        if (e < NE) {
            int src = __builtin_nontemporal_load(ei + e);
            int dst = __builtin_nontemporal_load(ei + NE + e);
            int r   = __builtin_nontemporal_load(et + e);
            bk[j] = dst >> BSH;
            pk[j] = (u32)src | ((u32)r << 17) | ((u32)(dst & 255) << 19);
            rank[j] = atomicAdd(&hist[bk[j]], 1);
        }
    }
    __syncthreads();
    for (int i = t; i < NB; i += 256) {
        int h = hist[i];
        base[i] = h ? atomicAdd(&bcnt[i], h) : 0;
    }
    __syncthreads();
#pragma unroll
    for (int j = 0; j < 16; ++j)
        if (bk[j] >= 0) bpack[(size_t)bk[j] * CAPB + base[bk[j]] + rank[j]] = pk[j];
}

// ---------- phase 2: per-bucket key sort with PER-NODE PADDING to x8 ----------
__global__ __launch_bounds__(256) void key_scatter(const int* __restrict__ bcnt,
                                                   const u32* __restrict__ bpack,
                                                   int* __restrict__ offs6,
                                                   int* __restrict__ spack) {
    __shared__ int hist[1024];
    __shared__ int sm[256];
    int b = blockIdx.x, t = threadIdx.x;
    int cnt = bcnt[b];
    const u32* seg = bpack + (size_t)b * CAPB;
#pragma unroll
    for (int j = 0; j < 4; ++j) hist[t + j * 256] = 0;
    __syncthreads();
    for (int i = t; i < cnt; i += 256) atomicAdd(&hist[seg[i] >> 17], 1);
    __syncthreads();
    int t4 = t * 4;
    int h0 = hist[t4], h1 = hist[t4 + 1], h2 = hist[t4 + 2], h3 = hist[t4 + 3];
    int s = h0 + h1 + h2 + h3;
    int sp = (s + 7) & ~7;            // node range padded to multiple of 8
    sm[t] = sp;
    __syncthreads();
    for (int o2 = 1; o2 < 256; o2 <<= 1) {
        int n = (t >= o2) ? sm[t - o2] : 0;
        __syncthreads();
        sm[t] += n;
        __syncthreads();
    }
    int bas = b * CAPB + sm[t] - sp;
    int e0 = bas, e1 = e0 + h0, e2 = e1 + h1, e3 = e2 + h2, e4 = e3 + h3, eL = bas + sp;
    int node = (b << 8) + t;
    if (node < NN) {
        int* o = offs6 + (size_t)node * 6;
        o[0] = e0; o[1] = e1; o[2] = e2; o[3] = e3; o[4] = e4; o[5] = eL;
    }
    hist[t4] = e0; hist[t4 + 1] = e1; hist[t4 + 2] = e2; hist[t4 + 3] = e3;
    for (int i = e4; i < eL; ++i) spack[i] = NN;   // pad -> dummy zero row
    __syncthreads();
    for (int i = t; i < cnt; i += 256) {
        u32 pk = seg[i];
        int pos = atomicAdd(&hist[pk >> 17], 1);
        spack[pos] = (int)(pk & 0x1FFFFu);
    }
}

// ---------- conversions / weight prep ----------
__global__ __launch_bounds__(256) void cvt_bf16(const float* __restrict__ in,
                                                u16* __restrict__ outp, int n) {
    int i = blockIdx.x * 256 + threadIdx.x;
    int idx = i * 4;
    if (idx >= n) return;
    float4 v = *(const float4*)(in + idx);
    u32 lo = (u32)f2b(v.x) | ((u32)f2b(v.y) << 16);
    u32 hi = (u32)f2b(v.z) | ((u32)f2b(v.w) << 16);
    *(uint2*)(outp + idx) = make_uint2(lo, hi);
}

__global__ __launch_bounds__(256) void prep_B(const float* __restrict__ Wrel,
                                              const float* __restrict__ Wroot,
                                              u16* __restrict__ Bt) {
    int i = blockIdx.x * 256 + threadIdx.x;
    if (i >= FD * KT) return;
    int k = i % KT;
    int o = i / KT;
    float v = (k < 512) ? Wrel[(size_t)k * FD + o] : Wroot[(size_t)(k - 512) * FD + o];
    Bt[i] = f2b(v);
}

// ---------- aggregation: one wave per row, padded CSR, all-scalar edge stream ----------
__global__ __launch_bounds__(256) void agg_kernel(const int* __restrict__ offs6,
                                                  const int* __restrict__ spack,
                                                  const u32* __restrict__ fp,   // u32[.][64], row NN = 0
                                                  u16* __restrict__ Aout,
                                                  int rows,
                                                  const int* __restrict__ nest,
                                                  const int* __restrict__ food,
                                                  int qmode,
                                                  int* __restrict__ qnodes) {
    int wid = threadIdx.x >> 6, lane = threadIdx.x & 63;
    int row = blockIdx.x * 4 + wid;
    if (row >= rows) return;
    int node;
    if (qmode) node = (row < NQ) ? nest[row] : food[row - NQ];
    else node = row;
    node = __builtin_amdgcn_readfirstlane(node);
    if (qmode && lane == 0) qnodes[row] = node;

    const int* ob = offs6 + (size_t)node * 6;
    int o0 = __builtin_amdgcn_readfirstlane(ob[0]);
    int o1 = __builtin_amdgcn_readfirstlane(ob[1]);
    int o2 = __builtin_amdgcn_readfirstlane(ob[2]);
    int o3 = __builtin_amdgcn_readfirstlane(ob[3]);
    int o4 = __builtin_amdgcn_readfirstlane(ob[4]);   // exact end of rel 3
    int oL = __builtin_amdgcn_readfirstlane(ob[5]);   // padded end (multiple of 8)

    float a00 = 0, a01 = 0, a10 = 0, a11 = 0, a20 = 0, a21 = 0, a30 = 0, a31 = 0;

    for (int e = o0; e < oL; e += 8) {
        int p[8];
        u32 v[8];
#pragma unroll
        for (int j = 0; j < 8; ++j)
            p[j] = __builtin_amdgcn_readfirstlane(spack[e + j]);   // uniform, contiguous
#pragma unroll
        for (int j = 0; j < 8; ++j) v[j] = fp[(size_t)p[j] * 64 + lane];
#pragma unroll
        for (int j = 0; j < 8; ++j) {
            int ij = e + j;                    // scalar
            float f0 = b2f_lo(v[j]);
            float f1 = b2f_hi(v[j]);
            if (ij < o1)      { a00 += f0; a01 += f1; }
            else if (ij < o2) { a10 += f0; a11 += f1; }
            else if (ij < o3) { a20 += f0; a21 += f1; }
            else              { a30 += f0; a31 += f1; }   // pads add 0.0 here
        }
    }

    int d0 = o1 - o0, d1 = o2 - o1, d2 = o3 - o2, d3 = o4 - o3;
    float s0 = 1.0f / (float)(d0 > 1 ? d0 : 1);
    float s1 = 1.0f / (float)(d1 > 1 ? d1 : 1);
    float s2 = 1.0f / (float)(d2 > 1 ? d2 : 1);
    float s3 = 1.0f / (float)(d3 > 1 ? d3 : 1);
    u16* Ao = Aout + (size_t)row * KA + lane * 2;
    __builtin_nontemporal_store(pack2(a00 * s0, a01 * s0), (u32*)(Ao + 0));
    __builtin_nontemporal_store(pack2(a10 * s1, a11 * s1), (u32*)(Ao + 128));
    __builtin_nontemporal_store(pack2(a20 * s2, a21 * s2), (u32*)(Ao + 256));
    __builtin_nontemporal_store(pack2(a30 * s3, a31 * s3), (u32*)(Ao + 384));
}

// ---------- GEMM: full-K LDS panel (80 KB), one stage volley, barrier-free K-loop ----------
// C[M,128] = act([A[M,512] | root[M,128]] @ Bt^T + bias). Block = 64 rows.
// Stage: each wave issues 20 x gload_lds (1 KB each) covering panel bytes
// [wid*20KB, wid*20KB+20KB); content XOR-swizzled via pre-swizzled GLOBAL src.
// One vmcnt(0)+barrier, then 20 K-steps: ds_read A-frags + L2-hot B (2-stage reg
// double buffer) + 8 MFMAs per wave per step. No further barriers.
__global__ __launch_bounds__(256) void gemm_fullk(const u16* __restrict__ A,
                                                  const u16* __restrict__ rootSrc,
                                                  const int* __restrict__ rootIdx,
                                                  const u16* __restrict__ Bt,
                                                  const float* __restrict__ bias,
                                                  void* __restrict__ Cout,
                                                  int M, int relu, int outBf16) {
    __shared__ u16 As[64 * KT];   // 80 KB
    char* lds = (char*)As;
    int tid = threadIdx.x;
    int wid = tid >> 6, lane = tid & 63;
    int wm = wid >> 1, wn = wid & 1;
    int lr = lane & 15, hi = lane >> 4;
    int row0 = blockIdx.x * 64;

    // ---- stage the whole 64x640 panel ----
#pragma unroll
    for (int i = 0; i < 20; ++i) {
        int b = (wid * 20 + i) * 1024 + lane * 16;   // LDS byte this lane fills
        int r = b / LROWB;                            // panel row
        int kb = b - r * LROWB;                       // byte-col within row (linear)
        int kbs = kb ^ ((r & 7) << 4);                // pre-swizzled source byte-col
        int gr = row0 + r;
        int idx = rootIdx ? ((kbs >= 1024) ? rootIdx[gr] : gr) : gr;
        const char* srcA = (const char*)A + (size_t)gr * (KA * 2) + kbs;
        const char* srcR = (const char*)rootSrc + (size_t)idx * (FD * 2) + (kbs - 1024);
        const char* src = (kbs < 1024) ? srcA : srcR;   // per-lane select, single issue
        gload_lds16(src, lds + (wid * 20 + i) * 1024);
    }
    __syncthreads();   // vmcnt(0) drain + barrier: panel resident

    f32x4 acc[2][4];
#pragma unroll
    for (int i = 0; i < 2; ++i)
#pragma unroll
        for (int j = 0; j < 4; ++j) acc[i][j] = (f32x4){0.f, 0.f, 0.f, 0.f};

    const u16* bp[4];
#pragma unroll
    for (int ni = 0; ni < 4; ++ni)
        bp[ni] = Bt + (size_t)(wn * 64 + ni * 16 + lr) * KT + hi * 8;

    bf16x8 bfr[2][4];
#pragma unroll
    for (int ni = 0; ni < 4; ++ni) bfr[0][ni] = *reinterpret_cast<const bf16x8*>(bp[ni]);

#pragma unroll
    for (int ks = 0; ks < 20; ++ks) {
        int cur = ks & 1;
        if (ks + 1 < 20) {
#pragma unroll
            for (int ni = 0; ni < 4; ++ni)
                bfr[cur ^ 1][ni] = *reinterpret_cast<const bf16x8*>(bp[ni] + (ks + 1) * 32);
        }
        bf16x8 afr[2];
#pragma unroll
        for (int mi = 0; mi < 2; ++mi) {
            int rr = wm * 32 + mi * 16 + lr;
            afr[mi] = *reinterpret_cast<const bf16x8*>(
                lds + rr * LROWB + ((ks * 64 + hi * 16) ^ ((rr & 7) << 4)));
        }
#pragma unroll
        for (int mi = 0; mi < 2; ++mi)
#pragma unroll
            for (int ni = 0; ni < 4; ++ni)
                acc[mi][ni] = __builtin_amdgcn_mfma_f32_16x16x32_bf16(afr[mi], bfr[cur][ni], acc[mi][ni], 0, 0, 0);
    }

    // epilogue: D col = lane&15, row = 4*(lane>>4)+reg
#pragma unroll
    for (int mi = 0; mi < 2; ++mi) {
#pragma unroll
        for (int ni = 0; ni < 4; ++ni) {
            int col = wn * 64 + ni * 16 + lr;
            float bv = bias[col];
#pragma unroll
            for (int rg = 0; rg < 4; ++rg) {
                int row = row0 + wm * 32 + mi * 16 + hi * 4 + rg;
                if (row < M) {
                    float v = acc[mi][ni][rg] + bv;
                    if (relu) v = fmaxf(v, 0.f);
                    if (outBf16) ((u16*)Cout)[(size_t)row * FD + col] = f2b(v);
                    else ((float*)Cout)[(size_t)row * FD + col] = v;
                }
            }
        }
    }
}

// ---------- final FC ----------
__global__ __launch_bounds__(256) void fc_kernel(const float* __restrict__ h2q,
                                                 const float* __restrict__ Wfc,
                                                 const float* __restrict__ bfc,
                                                 float* __restrict__ out) {
    __shared__ float comb[2 * FD];
    int q = blockIdx.x, t = threadIdx.x;
    if (t < FD) comb[t] = h2q[(size_t)q * FD + t];
    else comb[t] = h2q[(size_t)(NQ + q) * FD + (t - FD)];
    __syncthreads();
    float s = bfc[t];
#pragma unroll 4
    for (int k = 0; k < 2 * FD; ++k) s += comb[k] * Wfc[(size_t)k * HIDN + t];
    out[(size_t)q * HIDN + t] = fmaxf(s, 0.f);
}

extern "C" void kernel_launch(void* const* d_in, const int* in_sizes, int n_in,
                              void* d_out, int out_size, void* d_ws, size_t ws_size,
                              hipStream_t stream) {
    const float* x      = (const float*)d_in[0];
    const int*   ei     = (const int*)d_in[1];
    const int*   et     = (const int*)d_in[2];
    const int*   nest   = (const int*)d_in[3];
    const int*   food   = (const int*)d_in[4];
    const float* Wrel1  = (const float*)d_in[5];
    const float* Wroot1 = (const float*)d_in[6];
    const float* b1     = (const float*)d_in[7];
    const float* Wrel2  = (const float*)d_in[8];
    const float* Wroot2 = (const float*)d_in[9];
    const float* b2     = (const float*)d_in[10];
    const float* Wfc    = (const float*)d_in[11];
    const float* bfc    = (const float*)d_in[12];
    float* out = (float*)d_out;

    char* w = (char*)d_ws;
    size_t off = 0;
    auto take = [&](size_t b) {
        char* p = w + off;
        off += b;
        off = (off + 255) & ~(size_t)255;
        return p;
    };
    int* bcnt   = (int*)take((size_t)NB * 4);
    int* offs6  = (int*)take((size_t)NN * 6 * 4);
    u32* bpack  = (u32*)take((size_t)NB * CAPB * 4);
    int* spack  = (int*)take((size_t)NB * CAPB * 4);
    int* qnodes = (int*)take((size_t)2 * NQ * 4);
    u16* xh     = (u16*)take((size_t)MPAD * FD * 2);   // row NN = zeros (dummy row)
    u16* h1     = (u16*)take((size_t)MPAD * FD * 2);   // row NN = zeros (dummy row)
    u16* Bt1    = (u16*)take((size_t)FD * KT * 2);
    u16* Bt2    = (u16*)take((size_t)FD * KT * 2);
    u16* A1     = (u16*)take((size_t)MPAD * KA * 2);
    u16* A2     = (u16*)take((size_t)2 * NQ * KA * 2);
    float* h2q  = (float*)take((size_t)2 * NQ * FD * 4);

    hipMemsetAsync(bcnt, 0, (size_t)NB * 4, stream);
    hipMemsetAsync(xh + (size_t)NN * FD, 0, FD * 2, stream);   // zero dummy row
    hipMemsetAsync(h1 + (size_t)NN * FD, 0, FD * 2, stream);   // zero dummy row
    cvt_bf16<<<((NN * FD / 4) + 255) / 256, 256, 0, stream>>>(x, xh, NN * FD);
    prep_B<<<(FD * KT + 255) / 256, 256, 0, stream>>>(Wrel1, Wroot1, Bt1);
    prep_B<<<(FD * KT + 255) / 256, 256, 0, stream>>>(Wrel2, Wroot2, Bt2);
    bucket_scatter<<<NBLK1, 256, 0, stream>>>(ei, et, bcnt, bpack);
    key_scatter<<<NB, 256, 0, stream>>>(bcnt, bpack, offs6, spack);

    agg_kernel<<<(NN + 3) / 4, 256, 0, stream>>>(offs6, spack, (const u32*)xh, A1,
                                                 NN, nullptr, nullptr, 0, nullptr);
    gemm_fullk<<<MPAD / 64, 256, 0, stream>>>(A1, xh, nullptr, Bt1, b1,
                                              (void*)h1, NN, 1, 1);

    agg_kernel<<<(2 * NQ + 3) / 4, 256, 0, stream>>>(offs6, spack, (const u32*)h1, A2,
                                                     2 * NQ, nest, food, 1, qnodes);
    gemm_fullk<<<(2 * NQ) / 64, 256, 0, stream>>>(A2, h1, qnodes, Bt2, b2,
                                                  (void*)h2q, 2 * NQ, 0, 0);
    fc_kernel<<<NQ, 256, 0, stream>>>(h2q, Wfc, bfc, out);
}

// Round 17
// 259.778 us; speedup vs baseline: 1.1163x; 1.1163x over previous
//
#include <hip/hip_runtime.h>
#include <stdint.h>

#define NN 100000
#define NE 1600000
#define NR 4
#define NK (NN * NR)
#define FD 128
#define KA 512            // A matrix cols (rel blocks only; root handled separately)
#define KT 640
#define NQ 1024
#define HIDN 256

#define NB 391            // dst buckets of 256 nodes
#define BSH 8
#define CAPB 8192         // per-bucket capacity (edges; avg 4096 + pad <= ~6200)
#define EPB 4096
#define NBLK1 ((NE + EPB - 1) / EPB)   // 391
#define MPAD 100096                    // NN rounded up to 128

using u16 = unsigned short;
using u32 = unsigned int;
typedef __attribute__((ext_vector_type(8))) __bf16 bf16x8;
typedef __attribute__((ext_vector_type(4))) float f32x4;

__device__ __forceinline__ u16 f2b(float f) {
    u32 u = __builtin_bit_cast(u32, f);
    u32 r = u + 0x7FFFu + ((u >> 16) & 1u);   // round-to-nearest-even
    return (u16)(r >> 16);
}
__device__ __forceinline__ float b2f_lo(u32 v) { return __builtin_bit_cast(float, v << 16); }
__device__ __forceinline__ float b2f_hi(u32 v) { return __builtin_bit_cast(float, v & 0xFFFF0000u); }
__device__ __forceinline__ u32 pack2(float a, float b) {
    return (u32)f2b(a) | ((u32)f2b(b) << 16);
}
// async global->LDS, 16B per lane; LDS dest = wave-uniform base + lane*16
__device__ __forceinline__ void gload_lds16(const void* g, void* l) {
    __builtin_amdgcn_global_load_lds((const __attribute__((address_space(1))) u32*)g,
                                     (__attribute__((address_space(3))) u32*)l, 16, 0, 0);
}

// ---------- phase 1: bucket scatter into fixed-capacity bucket-major segments ----------
__global__ __launch_bounds__(256) void bucket_scatter(const int* __restrict__ ei,
                                                      const int* __restrict__ et,
                                                      int* __restrict__ bcnt,
                                                      u32* __restrict__ bpack) {
    __shared__ int hist[NB];
    __shared__ int base[NB];
    int t = threadIdx.x;
    for (int i = t; i < NB; i += 256) hist[i] = 0;
    __syncthreads();
    int e0 = blockIdx.x * EPB;
    int rank[16];
    u32 pk[16];
    int bk[16];
#pragma unroll
    for (int j = 0; j < 16; ++j) {
        int e = e0 + j * 256 + t;
        bk[j] = -1;
        if (e < NE) {
            int src = __builtin_nontemporal_load(ei + e);
            int dst = __builtin_nontemporal_load(ei + NE + e);
            int r   = __builtin_nontemporal_load(et + e);
            bk[j] = dst >> BSH;
            pk[j] = (u32)src | ((u32)r << 17) | ((u32)(dst & 255) << 19);
            rank[j] = atomicAdd(&hist[bk[j]], 1);
        }
    }
    __syncthreads();
    for (int i = t; i < NB; i += 256) {
        int h = hist[i];
        base[i] = h ? atomicAdd(&bcnt[i], h) : 0;
    }
    __syncthreads();
#pragma unroll
    for (int j = 0; j < 16; ++j)
        if (bk[j] >= 0) bpack[(size_t)bk[j] * CAPB + base[bk[j]] + rank[j]] = pk[j];
}

// ---------- phase 2: per-bucket key sort with PER-NODE PADDING to x8 ----------
__global__ __launch_bounds__(256) void key_scatter(const int* __restrict__ bcnt,
                                                   const u32* __restrict__ bpack,
                                                   int* __restrict__ offs6,
                                                   int* __restrict__ spack) {
    __shared__ int hist[1024];
    __shared__ int sm[256];
    int b = blockIdx.x, t = threadIdx.x;
    int cnt = bcnt[b];
    const u32* seg = bpack + (size_t)b * CAPB;
#pragma unroll
    for (int j = 0; j < 4; ++j) hist[t + j * 256] = 0;
    __syncthreads();
    for (int i = t; i < cnt; i += 256) atomicAdd(&hist[seg[i] >> 17], 1);
    __syncthreads();
    int t4 = t * 4;
    int h0 = hist[t4], h1 = hist[t4 + 1], h2 = hist[t4 + 2], h3 = hist[t4 + 3];
    int s = h0 + h1 + h2 + h3;
    int sp = (s + 7) & ~7;            // node range padded to multiple of 8
    sm[t] = sp;
    __syncthreads();
    for (int o2 = 1; o2 < 256; o2 <<= 1) {
        int n = (t >= o2) ? sm[t - o2] : 0;
        __syncthreads();
        sm[t] += n;
        __syncthreads();
    }
    int bas = b * CAPB + sm[t] - sp;
    int e0 = bas, e1 = e0 + h0, e2 = e1 + h1, e3 = e2 + h2, e4 = e3 + h3, eL = bas + sp;
    int node = (b << 8) + t;
    if (node < NN) {
        int* o = offs6 + (size_t)node * 6;
        o[0] = e0; o[1] = e1; o[2] = e2; o[3] = e3; o[4] = e4; o[5] = eL;
    }
    hist[t4] = e0; hist[t4 + 1] = e1; hist[t4 + 2] = e2; hist[t4 + 3] = e3;
    for (int i = e4; i < eL; ++i) spack[i] = NN;   // pad -> dummy zero row
    __syncthreads();
    for (int i = t; i < cnt; i += 256) {
        u32 pk = seg[i];
        int pos = atomicAdd(&hist[pk >> 17], 1);
        spack[pos] = (int)(pk & 0x1FFFFu);
    }
}

// ---------- conversions / weight prep ----------
__global__ __launch_bounds__(256) void cvt_bf16(const float* __restrict__ in,
                                                u16* __restrict__ outp, int n) {
    int i = blockIdx.x * 256 + threadIdx.x;
    int idx = i * 4;
    if (idx >= n) return;
    float4 v = *(const float4*)(in + idx);
    u32 lo = (u32)f2b(v.x) | ((u32)f2b(v.y) << 16);
    u32 hi = (u32)f2b(v.z) | ((u32)f2b(v.w) << 16);
    *(uint2*)(outp + idx) = make_uint2(lo, hi);
}

__global__ __launch_bounds__(256) void prep_B(const float* __restrict__ Wrel,
                                              const float* __restrict__ Wroot,
                                              u16* __restrict__ Bt) {
    int i = blockIdx.x * 256 + threadIdx.x;
    if (i >= FD * KT) return;
    int k = i % KT;
    int o = i / KT;
    float v = (k < 512) ? Wrel[(size_t)k * FD + o] : Wroot[(size_t)(k - 512) * FD + o];
    Bt[i] = f2b(v);
}

// ---------- aggregation: one wave per row, padded CSR, all-scalar edge stream ----------
__global__ __launch_bounds__(256) void agg_kernel(const int* __restrict__ offs6,
                                                  const int* __restrict__ spack,
                                                  const u32* __restrict__ fp,   // u32[.][64], row NN = 0
                                                  u16* __restrict__ Aout,
                                                  int rows,
                                                  const int* __restrict__ nest,
                                                  const int* __restrict__ food,
                                                  int qmode,
                                                  int* __restrict__ qnodes) {
    int wid = threadIdx.x >> 6, lane = threadIdx.x & 63;
    int row = blockIdx.x * 4 + wid;
    if (row >= rows) return;
    int node;
    if (qmode) node = (row < NQ) ? nest[row] : food[row - NQ];
    else node = row;
    node = __builtin_amdgcn_readfirstlane(node);
    if (qmode && lane == 0) qnodes[row] = node;

    const int* ob = offs6 + (size_t)node * 6;
    int o0 = __builtin_amdgcn_readfirstlane(ob[0]);
    int o1 = __builtin_amdgcn_readfirstlane(ob[1]);
    int o2 = __builtin_amdgcn_readfirstlane(ob[2]);
    int o3 = __builtin_amdgcn_readfirstlane(ob[3]);
    int o4 = __builtin_amdgcn_readfirstlane(ob[4]);   // exact end of rel 3
    int oL = __builtin_amdgcn_readfirstlane(ob[5]);   // padded end (multiple of 8)

    float a00 = 0, a01 = 0, a10 = 0, a11 = 0, a20 = 0, a21 = 0, a30 = 0, a31 = 0;

    for (int e = o0; e < oL; e += 8) {
        int p[8];
        u32 v[8];
#pragma unroll
        for (int j = 0; j < 8; ++j)
            p[j] = __builtin_amdgcn_readfirstlane(spack[e + j]);   // uniform, contiguous
#pragma unroll
        for (int j = 0; j < 8; ++j) v[j] = fp[(size_t)p[j] * 64 + lane];
#pragma unroll
        for (int j = 0; j < 8; ++j) {
            int ij = e + j;                    // scalar
            float f0 = b2f_lo(v[j]);
            float f1 = b2f_hi(v[j]);
            if (ij < o1)      { a00 += f0; a01 += f1; }
            else if (ij < o2) { a10 += f0; a11 += f1; }
            else if (ij < o3) { a20 += f0; a21 += f1; }
            else              { a30 += f0; a31 += f1; }   // pads add 0.0 here
        }
    }

    int d0 = o1 - o0, d1 = o2 - o1, d2 = o3 - o2, d3 = o4 - o3;
    float s0 = 1.0f / (float)(d0 > 1 ? d0 : 1);
    float s1 = 1.0f / (float)(d1 > 1 ? d1 : 1);
    float s2 = 1.0f / (float)(d2 > 1 ? d2 : 1);
    float s3 = 1.0f / (float)(d3 > 1 ? d3 : 1);
    u16* Ao = Aout + (size_t)row * KA + lane * 2;
    __builtin_nontemporal_store(pack2(a00 * s0, a01 * s0), (u32*)(Ao + 0));
    __builtin_nontemporal_store(pack2(a10 * s1, a11 * s1), (u32*)(Ao + 128));
    __builtin_nontemporal_store(pack2(a20 * s2, a21 * s2), (u32*)(Ao + 256));
    __builtin_nontemporal_store(pack2(a30 * s3, a31 * s3), (u32*)(Ao + 384));
}

// ---------- GEMM: 128-row blocks, 3-buffer LDS pipeline, counted vmcnt (T3/T4) ----------
// C[M,128] = act([A[M,512] | root[M,128]] @ Bt^T + bias), 10 K-iters of 64.
// Per iter t: issue B(t) frags FIRST -> issue stage(t+2) (stays in flight) ->
// s_waitcnt vmcnt(4) [drains through B(t), leaves stage(t+2)] -> raw s_barrier ->
// ds_read + 16 MFMA on buf t%3 -> raw s_barrier. Never vmcnt(0) mid-loop.
__global__ __launch_bounds__(256) void gemm_lds3(const u16* __restrict__ A,
                                                 const u16* __restrict__ rootSrc,
                                                 const int* __restrict__ rootIdx,
                                                 const u16* __restrict__ Bt,
                                                 const float* __restrict__ bias,
                                                 void* __restrict__ Cout,
                                                 int M, int relu, int outBf16) {
    __shared__ u16 As[3][8192];   // 3 x 16 KB: [128][64] bf16, swizzled content
    int tid = threadIdx.x;
    int wid = tid >> 6, lane = tid & 63;
    int wm = wid >> 1, wn = wid & 1;
    int lr = lane & 15, hi = lane >> 4;
    int row0 = blockIdx.x * 128;

    f32x4 acc[4][4];
#pragma unroll
    for (int i = 0; i < 4; ++i)
#pragma unroll
        for (int j = 0; j < 4; ++j) acc[i][j] = (f32x4){0.f, 0.f, 0.f, 0.f};

    int srow = wid * 8 + (lane >> 3);
    int sg = (lane & 7) ^ ((lane >> 3) & 7);   // pre-swizzled k-slot ((r&7) == srow&7)

    auto stage = [&](int t, int buf) {
#pragma unroll
        for (int i = 0; i < 4; ++i) {
            int r = i * 32 + srow;
            int gr = row0 + r;
            const u16* src;
            if (t < 8) {
                src = A + (size_t)gr * KA + t * 64 + sg * 8;
            } else {
                int idx = rootIdx ? rootIdx[gr] : gr;
                src = rootSrc + (size_t)idx * FD + (t - 8) * 64 + sg * 8;
            }
            gload_lds16(src, (char*)As[buf] + i * 4096 + wid * 1024);
        }
    };

    stage(0, 0);
    stage(1, 1);

    for (int t = 0; t < 10; ++t) {
        int cur = t % 3;
        // ---- B fragments for iter t (issued FIRST: older than the new stage) ----
        bf16x8 bfr[2][4];
#pragma unroll
        for (int kk = 0; kk < 2; ++kk)
#pragma unroll
            for (int ni = 0; ni < 4; ++ni) {
                int col = wn * 64 + ni * 16 + lr;
                bfr[kk][ni] = *reinterpret_cast<const bf16x8*>(
                    Bt + (size_t)col * KT + t * 64 + kk * 32 + hi * 8);
            }
        // ---- stage tile t+2 into buf (t+2)%3 (freed: held t-1, consumed last iter) ----
        bool staged = (t + 2 < 10);
        if (staged) stage(t + 2, (t + 2) % 3);
        // ---- counted drain: everything through B(t) done; stage(t+2) stays in flight ----
        if (staged) asm volatile("s_waitcnt vmcnt(4)" ::: "memory");
        else        asm volatile("s_waitcnt vmcnt(0)" ::: "memory");
        __builtin_amdgcn_s_barrier();            // all waves' stage(t) writes visible
        __builtin_amdgcn_sched_barrier(0);       // rule 18: no hoisting above the wait
        // ---- ds_read + MFMA on buffer t%3 ----
#pragma unroll
        for (int kk = 0; kk < 2; ++kk) {
            bf16x8 afr[4];
#pragma unroll
            for (int mi = 0; mi < 4; ++mi) {
                int r = wm * 64 + mi * 16 + lr;
                int sp = (kk * 4 + hi) ^ (r & 7);
                afr[mi] = *reinterpret_cast<const bf16x8*>((char*)As[cur] + r * 128 + sp * 16);
            }
#pragma unroll
            for (int mi = 0; mi < 4; ++mi)
#pragma unroll
                for (int ni = 0; ni < 4; ++ni)
                    acc[mi][ni] = __builtin_amdgcn_mfma_f32_16x16x32_bf16(afr[mi], bfr[kk][ni], acc[mi][ni], 0, 0, 0);
        }
        asm volatile("s_waitcnt lgkmcnt(0)" ::: "memory");   // ds_reads of buf done
        __builtin_amdgcn_s_barrier();            // buf t%3 free for reuse next iter
    }

    // epilogue: D col = lane&15, row = 4*(lane>>4)+reg
#pragma unroll
    for (int mi = 0; mi < 4; ++mi) {
#pragma unroll
        for (int ni = 0; ni < 4; ++ni) {
            int col = wn * 64 + ni * 16 + lr;
            float bv = bias[col];
#pragma unroll
            for (int rg = 0; rg < 4; ++rg) {
                int row = row0 + wm * 64 + mi * 16 + hi * 4 + rg;
                if (row < M) {
                    float v = acc[mi][ni][rg] + bv;
                    if (relu) v = fmaxf(v, 0.f);
                    if (outBf16) ((u16*)Cout)[(size_t)row * FD + col] = f2b(v);
                    else ((float*)Cout)[(size_t)row * FD + col] = v;
                }
            }
        }
    }
}

// ---------- final FC ----------
__global__ __launch_bounds__(256) void fc_kernel(const float* __restrict__ h2q,
                                                 const float* __restrict__ Wfc,
                                                 const float* __restrict__ bfc,
                                                 float* __restrict__ out) {
    __shared__ float comb[2 * FD];
    int q = blockIdx.x, t = threadIdx.x;
    if (t < FD) comb[t] = h2q[(size_t)q * FD + t];
    else comb[t] = h2q[(size_t)(NQ + q) * FD + (t - FD)];
    __syncthreads();
    float s = bfc[t];
#pragma unroll 4
    for (int k = 0; k < 2 * FD; ++k) s += comb[k] * Wfc[(size_t)k * HIDN + t];
    out[(size_t)q * HIDN + t] = fmaxf(s, 0.f);
}

extern "C" void kernel_launch(void* const* d_in, const int* in_sizes, int n_in,
                              void* d_out, int out_size, void* d_ws, size_t ws_size,
                              hipStream_t stream) {
    const float* x      = (const float*)d_in[0];
    const int*   ei     = (const int*)d_in[1];
    const int*   et     = (const int*)d_in[2];
    const int*   nest   = (const int*)d_in[3];
    const int*   food   = (const int*)d_in[4];
    const float* Wrel1  = (const float*)d_in[5];
    const float* Wroot1 = (const float*)d_in[6];
    const float* b1     = (const float*)d_in[7];
    const float* Wrel2  = (const float*)d_in[8];
    const float* Wroot2 = (const float*)d_in[9];
    const float* b2     = (const float*)d_in[10];
    const float* Wfc    = (const float*)d_in[11];
    const float* bfc    = (const float*)d_in[12];
    float* out = (float*)d_out;

    char* w = (char*)d_ws;
    size_t off = 0;
    auto take = [&](size_t b) {
        char* p = w + off;
        off += b;
        off = (off + 255) & ~(size_t)255;
        return p;
    };
    int* bcnt   = (int*)take((size_t)NB * 4);
    int* offs6  = (int*)take((size_t)NN * 6 * 4);
    u32* bpack  = (u32*)take((size_t)NB * CAPB * 4);
    int* spack  = (int*)take((size_t)NB * CAPB * 4);
    int* qnodes = (int*)take((size_t)2 * NQ * 4);
    u16* xh     = (u16*)take((size_t)MPAD * FD * 2);   // row NN = zeros (dummy row)
    u16* h1     = (u16*)take((size_t)MPAD * FD * 2);   // row NN = zeros (dummy row)
    u16* Bt1    = (u16*)take((size_t)FD * KT * 2);
    u16* Bt2    = (u16*)take((size_t)FD * KT * 2);
    u16* A1     = (u16*)take((size_t)MPAD * KA * 2);
    u16* A2     = (u16*)take((size_t)2 * NQ * KA * 2);
    float* h2q  = (float*)take((size_t)2 * NQ * FD * 4);

    hipMemsetAsync(bcnt, 0, (size_t)NB * 4, stream);
    hipMemsetAsync(xh + (size_t)NN * FD, 0, FD * 2, stream);   // zero dummy row
    hipMemsetAsync(h1 + (size_t)NN * FD, 0, FD * 2, stream);   // zero dummy row
    cvt_bf16<<<((NN * FD / 4) + 255) / 256, 256, 0, stream>>>(x, xh, NN * FD);
    prep_B<<<(FD * KT + 255) / 256, 256, 0, stream>>>(Wrel1, Wroot1, Bt1);
    prep_B<<<(FD * KT + 255) / 256, 256, 0, stream>>>(Wrel2, Wroot2, Bt2);
    bucket_scatter<<<NBLK1, 256, 0, stream>>>(ei, et, bcnt, bpack);
    key_scatter<<<NB, 256, 0, stream>>>(bcnt, bpack, offs6, spack);

    agg_kernel<<<(NN + 3) / 4, 256, 0, stream>>>(offs6, spack, (const u32*)xh, A1,
                                                 NN, nullptr, nullptr, 0, nullptr);
    gemm_lds3<<<MPAD / 128, 256, 0, stream>>>(A1, xh, nullptr, Bt1, b1,
                                              (void*)h1, NN, 1, 1);

    agg_kernel<<<(2 * NQ + 3) / 4, 256, 0, stream>>>(offs6, spack, (const u32*)h1, A2,
                                                     2 * NQ, nest, food, 1, qnodes);
    gemm_lds3<<<(2 * NQ) / 128, 256, 0, stream>>>(A2, h1, qnodes, Bt2, b2,
                                                  (void*)h2q, 2 * NQ, 0, 0);
    fc_kernel<<<NQ, 256, 0, stream>>>(h2q, Wfc, bfc, out);
}

// Round 18
// 252.969 us; speedup vs baseline: 1.1463x; 1.0269x over previous
//
#include <hip/hip_runtime.h>
#include <stdint.h>

#define NN 100000
#define NE 1600000
#define NR 4
#define NK (NN * NR)
#define FD 128
#define KA 512            // layer-2 A matrix cols (rel blocks only)
#define KT 640
#define NQ 1024
#define HIDN 256

#define NB 391            // dst buckets of 256 nodes
#define BSH 8
#define CAPB 8192         // per-bucket capacity (edges; avg 4096 + pad <= ~6200)
#define EPB 4096
#define NBLK1 ((NE + EPB - 1) / EPB)   // 391
#define MPAD 100096                    // NN rounded up to 128
#define NCHK (MPAD / 128)              // 782 row-chunks per table

using u16 = unsigned short;
using u32 = unsigned int;
typedef __attribute__((ext_vector_type(8))) __bf16 bf16x8;
typedef __attribute__((ext_vector_type(4))) float f32x4;

__device__ __forceinline__ u16 f2b(float f) {
    u32 u = __builtin_bit_cast(u32, f);
    u32 r = u + 0x7FFFu + ((u >> 16) & 1u);   // round-to-nearest-even
    return (u16)(r >> 16);
}
__device__ __forceinline__ float b2f_lo(u32 v) { return __builtin_bit_cast(float, v << 16); }
__device__ __forceinline__ float b2f_hi(u32 v) { return __builtin_bit_cast(float, v & 0xFFFF0000u); }
__device__ __forceinline__ u32 pack2(float a, float b) {
    return (u32)f2b(a) | ((u32)f2b(b) << 16);
}
// async global->LDS, 16B per lane; LDS dest = wave-uniform base + lane*16
__device__ __forceinline__ void gload_lds16(const void* g, void* l) {
    __builtin_amdgcn_global_load_lds((const __attribute__((address_space(1))) u32*)g,
                                     (__attribute__((address_space(3))) u32*)l, 16, 0, 0);
}

// ---------- phase 1: bucket scatter into fixed-capacity bucket-major segments ----------
__global__ __launch_bounds__(256) void bucket_scatter(const int* __restrict__ ei,
                                                      const int* __restrict__ et,
                                                      int* __restrict__ bcnt,
                                                      u32* __restrict__ bpack) {
    __shared__ int hist[NB];
    __shared__ int base[NB];
    int t = threadIdx.x;
    for (int i = t; i < NB; i += 256) hist[i] = 0;
    __syncthreads();
    int e0 = blockIdx.x * EPB;
    int rank[16];
    u32 pk[16];
    int bk[16];
#pragma unroll
    for (int j = 0; j < 16; ++j) {
        int e = e0 + j * 256 + t;
        bk[j] = -1;
        if (e < NE) {
            int src = __builtin_nontemporal_load(ei + e);
            int dst = __builtin_nontemporal_load(ei + NE + e);
            int r   = __builtin_nontemporal_load(et + e);
            bk[j] = dst >> BSH;
            pk[j] = (u32)src | ((u32)r << 17) | ((u32)(dst & 255) << 19);
            rank[j] = atomicAdd(&hist[bk[j]], 1);
        }
    }
    __syncthreads();
    for (int i = t; i < NB; i += 256) {
        int h = hist[i];
        base[i] = h ? atomicAdd(&bcnt[i], h) : 0;
    }
    __syncthreads();
#pragma unroll
    for (int j = 0; j < 16; ++j)
        if (bk[j] >= 0) bpack[(size_t)bk[j] * CAPB + base[bk[j]] + rank[j]] = pk[j];
}

// ---------- phase 2: per-bucket key sort with PER-NODE PADDING to x8 ----------
// spackY[pos] = rel*NN + src  (direct Y-table row index); pad slots -> 5*NN (zero row).
__global__ __launch_bounds__(256) void key_scatter(const int* __restrict__ bcnt,
                                                   const u32* __restrict__ bpack,
                                                   int* __restrict__ offs6,
                                                   int* __restrict__ spackY) {
    __shared__ int hist[1024];
    __shared__ int sm[256];
    int b = blockIdx.x, t = threadIdx.x;
    int cnt = bcnt[b];
    const u32* seg = bpack + (size_t)b * CAPB;
#pragma unroll
    for (int j = 0; j < 4; ++j) hist[t + j * 256] = 0;
    __syncthreads();
    for (int i = t; i < cnt; i += 256) atomicAdd(&hist[seg[i] >> 17], 1);
    __syncthreads();
    int t4 = t * 4;
    int h0 = hist[t4], h1 = hist[t4 + 1], h2 = hist[t4 + 2], h3 = hist[t4 + 3];
    int s = h0 + h1 + h2 + h3;
    int sp = (s + 7) & ~7;            // node range padded to multiple of 8
    sm[t] = sp;
    __syncthreads();
    for (int o2 = 1; o2 < 256; o2 <<= 1) {
        int n = (t >= o2) ? sm[t - o2] : 0;
        __syncthreads();
        sm[t] += n;
        __syncthreads();
    }
    int bas = b * CAPB + sm[t] - sp;
    int e0 = bas, e1 = e0 + h0, e2 = e1 + h1, e3 = e2 + h2, e4 = e3 + h3, eL = bas + sp;
    int node = (b << 8) + t;
    if (node < NN) {
        int* o = offs6 + (size_t)node * 6;
        o[0] = e0; o[1] = e1; o[2] = e2; o[3] = e3; o[4] = e4; o[5] = eL;
    }
    hist[t4] = e0; hist[t4 + 1] = e1; hist[t4 + 2] = e2; hist[t4 + 3] = e3;
    for (int i = e4; i < eL; ++i) spackY[i] = 5 * NN;   // pad -> Y zero row
    __syncthreads();
    for (int i = t; i < cnt; i += 256) {
        u32 pk = seg[i];
        int pos = atomicAdd(&hist[pk >> 17], 1);
        spackY[pos] = (int)(pk & 0x1FFFFu) + (int)((pk >> 17) & 3u) * NN;
    }
}

// ---------- conversions / weight prep ----------
__global__ __launch_bounds__(256) void cvt_bf16(const float* __restrict__ in,
                                                u16* __restrict__ outp, int n) {
    int i = blockIdx.x * 256 + threadIdx.x;
    int idx = i * 4;
    if (idx >= n) return;
    float4 v = *(const float4*)(in + idx);
    u32 lo = (u32)f2b(v.x) | ((u32)f2b(v.y) << 16);
    u32 hi = (u32)f2b(v.z) | ((u32)f2b(v.w) << 16);
    *(uint2*)(outp + idx) = make_uint2(lo, hi);
}

// Bt5[r][o][k] (r<4: Wrel[r][k][o]; r==4: Wroot[k][o]) — 5 x 32 KB tables, K=128
__global__ __launch_bounds__(256) void prep_B5(const float* __restrict__ Wrel,
                                               const float* __restrict__ Wroot,
                                               u16* __restrict__ Bt5) {
    int i = blockIdx.x * 256 + threadIdx.x;
    if (i >= 5 * FD * FD) return;
    int tb = i / (FD * FD);
    int rem = i - tb * (FD * FD);
    int o = rem / FD;
    int k = rem - o * FD;
    float v = (tb < 4) ? Wrel[(size_t)tb * FD * FD + (size_t)k * FD + o]
                       : Wroot[(size_t)k * FD + o];
    Bt5[i] = f2b(v);
}

// Bt2[o][k] KT-layout for the layer-2 GEMM (k<512: Wrel2; k>=512: Wroot2)
__global__ __launch_bounds__(256) void prep_B(const float* __restrict__ Wrel,
                                              const float* __restrict__ Wroot,
                                              u16* __restrict__ Bt) {
    int i = blockIdx.x * 256 + threadIdx.x;
    if (i >= FD * KT) return;
    int k = i % KT;
    int o = i / KT;
    float v = (k < 512) ? Wrel[(size_t)k * FD + o] : Wroot[(size_t)(k - 512) * FD + o];
    Bt[i] = f2b(v);
}

// ---------- gemm_y: Y[r] = X @ Bt5[r]^T, 5 tables x 782 chunks, K=128 upfront ----------
__global__ __launch_bounds__(256) void gemm_y(const u16* __restrict__ X,     // xh [MPAD][128]
                                              const u16* __restrict__ Bt5,   // [5][128][128]
                                              u16* __restrict__ Y) {         // [5*NN+1][128]
    __shared__ u16 As[2][8192];   // 2 x 16 KB: [128 rows][64 k], swizzled content
    int blk = blockIdx.x;
    int rel = blk / NCHK;
    int chunk = blk - rel * NCHK;
    int row0 = chunk * 128;
    int tid = threadIdx.x;
    int wid = tid >> 6, lane = tid & 63;
    int wm = wid >> 1, wn = wid & 1;
    int lr = lane & 15, hi = lane >> 4;
    const u16* Btr = Bt5 + (size_t)rel * FD * FD;
    u16* C = Y + (size_t)rel * NN * FD;

    int srow = wid * 8 + (lane >> 3);
    int sg = (lane & 7) ^ ((lane >> 3) & 7);
#pragma unroll
    for (int s = 0; s < 2; ++s)
#pragma unroll
        for (int i = 0; i < 4; ++i) {
            int r = i * 32 + srow;
            int gr = row0 + r;
            gload_lds16(X + (size_t)gr * FD + s * 64 + sg * 8,
                        (char*)As[s] + i * 4096 + wid * 1024);
        }
    __syncthreads();   // single drain: both K-tiles resident

    f32x4 acc[4][4];
#pragma unroll
    for (int i = 0; i < 4; ++i)
#pragma unroll
        for (int j = 0; j < 4; ++j) acc[i][j] = (f32x4){0.f, 0.f, 0.f, 0.f};

#pragma unroll
    for (int t = 0; t < 2; ++t) {
#pragma unroll
        for (int kk = 0; kk < 2; ++kk) {
            bf16x8 bfr[4], afr[4];
#pragma unroll
            for (int ni = 0; ni < 4; ++ni) {
                int col = wn * 64 + ni * 16 + lr;
                bfr[ni] = *reinterpret_cast<const bf16x8*>(
                    Btr + (size_t)col * FD + t * 64 + kk * 32 + hi * 8);
            }
#pragma unroll
            for (int mi = 0; mi < 4; ++mi) {
                int r = wm * 64 + mi * 16 + lr;
                int sp = (kk * 4 + hi) ^ (r & 7);
                afr[mi] = *reinterpret_cast<const bf16x8*>((char*)As[t] + r * 128 + sp * 16);
            }
#pragma unroll
            for (int mi = 0; mi < 4; ++mi)
#pragma unroll
                for (int ni = 0; ni < 4; ++ni)
                    acc[mi][ni] = __builtin_amdgcn_mfma_f32_16x16x32_bf16(afr[mi], bfr[ni], acc[mi][ni], 0, 0, 0);
        }
    }
#pragma unroll
    for (int mi = 0; mi < 4; ++mi)
#pragma unroll
        for (int ni = 0; ni < 4; ++ni) {
            int col = wn * 64 + ni * 16 + lr;
#pragma unroll
            for (int rg = 0; rg < 4; ++rg) {
                int row = row0 + wm * 64 + mi * 16 + hi * 4 + rg;
                if (row < NN) C[(size_t)row * FD + col] = f2b(acc[mi][ni][rg]);
            }
        }
}

// ---------- layer-1 aggregation: gather pre-transformed Y rows, write h1 directly ----------
__global__ __launch_bounds__(256) void agg_l1(const int* __restrict__ offs6,
                                              const int* __restrict__ spackY,
                                              const u32* __restrict__ Y,     // u32[5*NN+1][64], row 5*NN = 0
                                              const float* __restrict__ bias,
                                              u16* __restrict__ h1) {
    int wid = threadIdx.x >> 6, lane = threadIdx.x & 63;
    int node = blockIdx.x * 4 + wid;
    if (node >= NN) return;

    const int* ob = offs6 + (size_t)node * 6;
    int o0 = __builtin_amdgcn_readfirstlane(ob[0]);
    int o1 = __builtin_amdgcn_readfirstlane(ob[1]);
    int o2 = __builtin_amdgcn_readfirstlane(ob[2]);
    int o3 = __builtin_amdgcn_readfirstlane(ob[3]);
    int o4 = __builtin_amdgcn_readfirstlane(ob[4]);
    int oL = __builtin_amdgcn_readfirstlane(ob[5]);

    float a00 = 0, a01 = 0, a10 = 0, a11 = 0, a20 = 0, a21 = 0, a30 = 0, a31 = 0;

    for (int e = o0; e < oL; e += 8) {
        int p[8];
        u32 v[8];
#pragma unroll
        for (int j = 0; j < 8; ++j)
            p[j] = __builtin_amdgcn_readfirstlane(spackY[e + j]);
#pragma unroll
        for (int j = 0; j < 8; ++j) v[j] = Y[(size_t)p[j] * 64 + lane];
#pragma unroll
        for (int j = 0; j < 8; ++j) {
            int ij = e + j;
            float f0 = b2f_lo(v[j]);
            float f1 = b2f_hi(v[j]);
            if (ij < o1)      { a00 += f0; a01 += f1; }
            else if (ij < o2) { a10 += f0; a11 += f1; }
            else if (ij < o3) { a20 += f0; a21 += f1; }
            else              { a30 += f0; a31 += f1; }   // pads read zero row
        }
    }

    int d0 = o1 - o0, d1 = o2 - o1, d2 = o3 - o2, d3 = o4 - o3;
    float s0 = 1.0f / (float)(d0 > 1 ? d0 : 1);
    float s1 = 1.0f / (float)(d1 > 1 ? d1 : 1);
    float s2 = 1.0f / (float)(d2 > 1 ? d2 : 1);
    float s3 = 1.0f / (float)(d3 > 1 ? d3 : 1);
    float sum0 = a00 * s0 + a10 * s1 + a20 * s2 + a30 * s3;
    float sum1 = a01 * s0 + a11 * s1 + a21 * s2 + a31 * s3;
    u32 rv = Y[((size_t)4 * NN + node) * 64 + lane];    // root table row (coalesced)
    float2 bb = *reinterpret_cast<const float2*>(bias + lane * 2);
    float r0 = fmaxf(sum0 + b2f_lo(rv) + bb.x, 0.f);
    float r1 = fmaxf(sum1 + b2f_hi(rv) + bb.y, 0.f);
    *(u32*)(h1 + (size_t)node * FD + lane * 2) = pack2(r0, r1);
}

// ---------- layer-2 aggregation (2048 query rows): per-rel clamped sub-loops ----------
__global__ __launch_bounds__(256) void agg_q(const int* __restrict__ offs6,
                                             const int* __restrict__ spackY,
                                             const u32* __restrict__ fp,   // h1 u32 view, row NN = 0
                                             u16* __restrict__ Aout,
                                             const int* __restrict__ nest,
                                             const int* __restrict__ food,
                                             int* __restrict__ qnodes) {
    int wid = threadIdx.x >> 6, lane = threadIdx.x & 63;
    int row = blockIdx.x * 4 + wid;
    if (row >= 2 * NQ) return;
    int node = (row < NQ) ? nest[row] : food[row - NQ];
    node = __builtin_amdgcn_readfirstlane(node);
    if (lane == 0) qnodes[row] = node;
    const int* ob = offs6 + (size_t)node * 6;
    int o[5];
#pragma unroll
    for (int i = 0; i < 5; ++i) o[i] = __builtin_amdgcn_readfirstlane(ob[i]);
    u16* Ao = Aout + (size_t)row * KA + lane * 2;
#pragma unroll
    for (int r = 0; r < 4; ++r) {
        int s = o[r], t = o[r + 1], last = t - 1;
        float a0 = 0, a1 = 0;
        for (int e = s; e < t; e += 8) {
            int p[8];
            u32 v[8];
#pragma unroll
            for (int j = 0; j < 8; ++j) {
                int ij = e + j;
                int cl = ij <= last ? ij : last;
                int pv = __builtin_amdgcn_readfirstlane(spackY[cl]) - r * NN;  // back to src
                p[j] = (ij <= last) ? pv : NN;   // h1 zero row
            }
#pragma unroll
            for (int j = 0; j < 8; ++j) v[j] = fp[(size_t)p[j] * 64 + lane];
#pragma unroll
            for (int j = 0; j < 8; ++j) { a0 += b2f_lo(v[j]); a1 += b2f_hi(v[j]); }
        }
        int d = t - s;
        float sc = 1.0f / (float)(d > 1 ? d : 1);
        *(u32*)(Ao + r * 128) = pack2(a0 * sc, a1 * sc);
    }
}

// ---------- layer-2 GEMM (2048 rows): 3-buffer counted-vmcnt pipeline (r17) ----------
__global__ __launch_bounds__(256) void gemm_lds3(const u16* __restrict__ A,
                                                 const u16* __restrict__ rootSrc,
                                                 const int* __restrict__ rootIdx,
                                                 const u16* __restrict__ Bt,
                                                 const float* __restrict__ bias,
                                                 float* __restrict__ Cout, int M) {
    __shared__ u16 As[3][8192];
    int tid = threadIdx.x;
    int wid = tid >> 6, lane = tid & 63;
    int wm = wid >> 1, wn = wid & 1;
    int lr = lane & 15, hi = lane >> 4;
    int row0 = blockIdx.x * 128;

    f32x4 acc[4][4];
#pragma unroll
    for (int i = 0; i < 4; ++i)
#pragma unroll
        for (int j = 0; j < 4; ++j) acc[i][j] = (f32x4){0.f, 0.f, 0.f, 0.f};

    int srow = wid * 8 + (lane >> 3);
    int sg = (lane & 7) ^ ((lane >> 3) & 7);

    auto stage = [&](int t, int buf) {
#pragma unroll
        for (int i = 0; i < 4; ++i) {
            int r = i * 32 + srow;
            int gr = row0 + r;
            const u16* src;
            if (t < 8) {
                src = A + (size_t)gr * KA + t * 64 + sg * 8;
            } else {
                int idx = rootIdx[gr];
                src = rootSrc + (size_t)idx * FD + (t - 8) * 64 + sg * 8;
            }
            gload_lds16(src, (char*)As[buf] + i * 4096 + wid * 1024);
        }
    };

    stage(0, 0);
    stage(1, 1);

    for (int t = 0; t < 10; ++t) {
        int cur = t % 3;
        bf16x8 bfr[2][4];
#pragma unroll
        for (int kk = 0; kk < 2; ++kk)
#pragma unroll
            for (int ni = 0; ni < 4; ++ni) {
                int col = wn * 64 + ni * 16 + lr;
                bfr[kk][ni] = *reinterpret_cast<const bf16x8*>(
                    Bt + (size_t)col * KT + t * 64 + kk * 32 + hi * 8);
            }
        bool staged = (t + 2 < 10);
        if (staged) stage(t + 2, (t + 2) % 3);
        if (staged) asm volatile("s_waitcnt vmcnt(4)" ::: "memory");
        else        asm volatile("s_waitcnt vmcnt(0)" ::: "memory");
        __builtin_amdgcn_s_barrier();
        __builtin_amdgcn_sched_barrier(0);
#pragma unroll
        for (int kk = 0; kk < 2; ++kk) {
            bf16x8 afr[4];
#pragma unroll
            for (int mi = 0; mi < 4; ++mi) {
                int r = wm * 64 + mi * 16 + lr;
                int sp = (kk * 4 + hi) ^ (r & 7);
                afr[mi] = *reinterpret_cast<const bf16x8*>((char*)As[cur] + r * 128 + sp * 16);
            }
#pragma unroll
            for (int mi = 0; mi < 4; ++mi)
#pragma unroll
                for (int ni = 0; ni < 4; ++ni)
                    acc[mi][ni] = __builtin_amdgcn_mfma_f32_16x16x32_bf16(afr[mi], bfr[kk][ni], acc[mi][ni], 0, 0, 0);
        }
        asm volatile("s_waitcnt lgkmcnt(0)" ::: "memory");
        __builtin_amdgcn_s_barrier();
    }

#pragma unroll
    for (int mi = 0; mi < 4; ++mi)
#pragma unroll
        for (int ni = 0; ni < 4; ++ni) {
            int col = wn * 64 + ni * 16 + lr;
            float bv = bias[col];
#pragma unroll
            for (int rg = 0; rg < 4; ++rg) {
                int row = row0 + wm * 64 + mi * 16 + hi * 4 + rg;
                if (row < M) Cout[(size_t)row * FD + col] = acc[mi][ni][rg] + bv;
            }
        }
}

// ---------- final FC ----------
__global__ __launch_bounds__(256) void fc_kernel(const float* __restrict__ h2q,
                                                 const float* __restrict__ Wfc,
                                                 const float* __restrict__ bfc,
                                                 float* __restrict__ out) {
    __shared__ float comb[2 * FD];
    int q = blockIdx.x, t = threadIdx.x;
    if (t < FD) comb[t] = h2q[(size_t)q * FD + t];
    else comb[t] = h2q[(size_t)(NQ + q) * FD + (t - FD)];
    __syncthreads();
    float s = bfc[t];
#pragma unroll 4
    for (int k = 0; k < 2 * FD; ++k) s += comb[k] * Wfc[(size_t)k * HIDN + t];
    out[(size_t)q * HIDN + t] = fmaxf(s, 0.f);
}

extern "C" void kernel_launch(void* const* d_in, const int* in_sizes, int n_in,
                              void* d_out, int out_size, void* d_ws, size_t ws_size,
                              hipStream_t stream) {
    const float* x      = (const float*)d_in[0];
    const int*   ei     = (const int*)d_in[1];
    const int*   et     = (const int*)d_in[2];
    const int*   nest   = (const int*)d_in[3];
    const int*   food   = (const int*)d_in[4];
    const float* Wrel1  = (const float*)d_in[5];
    const float* Wroot1 = (const float*)d_in[6];
    const float* b1     = (const float*)d_in[7];
    const float* Wrel2  = (const float*)d_in[8];
    const float* Wroot2 = (const float*)d_in[9];
    const float* b2     = (const float*)d_in[10];
    const float* Wfc    = (const float*)d_in[11];
    const float* bfc    = (const float*)d_in[12];
    float* out = (float*)d_out;

    char* w = (char*)d_ws;
    size_t off = 0;
    auto take = [&](size_t b) {
        char* p = w + off;
        off += b;
        off = (off + 255) & ~(size_t)255;
        return p;
    };
    int* bcnt   = (int*)take((size_t)NB * 4);
    int* offs6  = (int*)take((size_t)NN * 6 * 4);
    u32* bpack  = (u32*)take((size_t)NB * CAPB * 4);
    int* spackY = (int*)take((size_t)NB * CAPB * 4);
    int* qnodes = (int*)take((size_t)2 * NQ * 4);
    u16* xh     = (u16*)take((size_t)MPAD * FD * 2);
    u16* h1     = (u16*)take((size_t)MPAD * FD * 2);        // row NN = zeros
    u16* Bt5    = (u16*)take((size_t)5 * FD * FD * 2);
    u16* Bt2    = (u16*)take((size_t)FD * KT * 2);
    u16* Y      = (u16*)take(((size_t)5 * NN + 1) * FD * 2); // row 5*NN = zeros
    u16* A2     = (u16*)take((size_t)2 * NQ * KA * 2);
    float* h2q  = (float*)take((size_t)2 * NQ * FD * 4);

    hipMemsetAsync(bcnt, 0, (size_t)NB * 4, stream);
    hipMemsetAsync(h1 + (size_t)NN * FD, 0, FD * 2, stream);          // h1 zero row
    hipMemsetAsync(Y + (size_t)5 * NN * FD, 0, FD * 2, stream);       // Y zero row
    cvt_bf16<<<((NN * FD / 4) + 255) / 256, 256, 0, stream>>>(x, xh, NN * FD);
    prep_B5<<<(5 * FD * FD + 255) / 256, 256, 0, stream>>>(Wrel1, Wroot1, Bt5);
    prep_B<<<(FD * KT + 255) / 256, 256, 0, stream>>>(Wrel2, Wroot2, Bt2);

    // Y tables (transform-first layer 1): 5 x 782 = 3910 blocks
    gemm_y<<<5 * NCHK, 256, 0, stream>>>(xh, Bt5, Y);

    bucket_scatter<<<NBLK1, 256, 0, stream>>>(ei, et, bcnt, bpack);
    key_scatter<<<NB, 256, 0, stream>>>(bcnt, bpack, offs6, spackY);

    // layer 1: gather pre-transformed rows -> h1 (no A1 matrix, no standalone GEMM)
    agg_l1<<<(NN + 3) / 4, 256, 0, stream>>>(offs6, spackY, (const u32*)Y, b1, h1);

    // layer 2 (2048 query rows): aggregate-first as before
    agg_q<<<(2 * NQ + 3) / 4, 256, 0, stream>>>(offs6, spackY, (const u32*)h1, A2,
                                                nest, food, qnodes);
    gemm_lds3<<<(2 * NQ) / 128, 256, 0, stream>>>(A2, h1, qnodes, Bt2, b2, h2q, 2 * NQ);
    fc_kernel<<<NQ, 256, 0, stream>>>(h2q, Wfc, bfc, out);
}